// Round 1
// baseline (244.250 us; speedup 1.0000x reference)
//
#include <hip/hip_runtime.h>
#include <hip/hip_bf16.h>

typedef __attribute__((ext_vector_type(8))) short short8;
typedef __attribute__((ext_vector_type(4))) float floatx4;

constexpr int Bsz = 4, Ssz = 1024, NXc = 1024, NHc = 16, HDc = 64;
constexpr int OUT_ELEMS  = Bsz * Ssz * NXc;        // 4194304
constexpr int HEAD_ELEMS = Bsz * NHc * Ssz * HDc;  // 4194304

union BF8 { __hip_bfloat16 h[8]; uint4 v; short8 s; };

__device__ __forceinline__ uint4 cvt8(const float* __restrict__ p) {
    float4 a = *reinterpret_cast<const float4*>(p);
    float4 b = *reinterpret_cast<const float4*>(p + 4);
    BF8 u;
    u.h[0] = __float2bfloat16(a.x); u.h[1] = __float2bfloat16(a.y);
    u.h[2] = __float2bfloat16(a.z); u.h[3] = __float2bfloat16(a.w);
    u.h[4] = __float2bfloat16(b.x); u.h[5] = __float2bfloat16(b.y);
    u.h[6] = __float2bfloat16(b.z); u.h[7] = __float2bfloat16(b.w);
    return u.v;
}

// async 16B global -> LDS (wave-uniform LDS base + lane*16)
__device__ __forceinline__ void load_lds_16B(const void* g, void* l) {
    __builtin_amdgcn_global_load_lds(
        (const __attribute__((address_space(1))) unsigned int*)g,
        (__attribute__((address_space(3))) unsigned int*)l, 16, 0, 0);
}

// ===========================================================================
// FAST PATH
// ===========================================================================

__global__ __launch_bounds__(256) void cvt_kernel(
    const float* __restrict__ in, __hip_bfloat16* __restrict__ out, int n)
{
    int i = (blockIdx.x * 256 + threadIdx.x) * 8;
    if (i < n)
        *reinterpret_cast<uint4*>(out + i) = cvt8(in + i);
}

// K x N fp32  ->  N x K bf16 (transpose + convert), 64x64 tiles
__global__ __launch_bounds__(256) void transpose_cvt(
    const float* __restrict__ in, __hip_bfloat16* __restrict__ out,
    int K, int N)
{
    __shared__ float t[64][65];
    const int tid = threadIdx.x;
    const int k0 = blockIdx.y * 64, n0 = blockIdx.x * 64;
#pragma unroll
    for (int j = 0; j < 16; ++j) {
        const int idx = tid + j * 256;
        const int row = idx >> 6, col = idx & 63;
        t[row][col] = in[(size_t)(k0 + row) * N + n0 + col];
    }
    __syncthreads();
#pragma unroll
    for (int j = 0; j < 16; ++j) {
        const int idx = tid + j * 256;
        const int orow = idx >> 6, ocol = idx & 63;
        out[(size_t)(n0 + orow) * K + k0 + ocol] = __float2bfloat16(t[ocol][orow]);
    }
}

// ---------------------------------------------------------------------------
// 128x128-tile bf16 GEMM, BK=32, global_load_lds staging (m97 structure).
// ---------------------------------------------------------------------------
template <int EPI>
__global__ __launch_bounds__(256) void gemm128(
    const __hip_bfloat16* __restrict__ A,
    const __hip_bfloat16* __restrict__ Bt,
    const float* __restrict__ bias,
    float* __restrict__ outf,
    __hip_bfloat16* __restrict__ qws,
    float* __restrict__ present,
    int M, int N, int K)
{
    __shared__ __align__(16) __hip_bfloat16 As[128 * 32];
    __shared__ __align__(16) __hip_bfloat16 Bs[128 * 32];

    const int tid  = threadIdx.x;
    const int w    = tid >> 6, lane = tid & 63;
    const int quad = lane >> 4, l16 = lane & 15;
    const int m0 = blockIdx.y * 128, n0 = blockIdx.x * 128;
    const int mb = (w >> 1) * 64, nbw = (w & 1) * 64;

    const int srow = lane >> 2;
    const int skseg = (lane & 3) * 8;

    floatx4 acc[4][4];
#pragma unroll
    for (int i = 0; i < 4; ++i)
#pragma unroll
        for (int j = 0; j < 4; ++j)
#pragma unroll
            for (int r = 0; r < 4; ++r) acc[i][j][r] = 0.f;

    for (int k0 = 0; k0 < K; k0 += 32) {
#pragma unroll
        for (int c = 0; c < 2; ++c) {
            const int chunk = w * 2 + c;
            const int row = chunk * 16 + srow;
            load_lds_16B(A + (size_t)(m0 + row) * K + k0 + skseg,
                         &As[chunk * 512]);
            load_lds_16B(Bt + (size_t)(n0 + row) * K + k0 + skseg,
                         &Bs[chunk * 512]);
        }
        __syncthreads();

        short8 af[4], bfr[4];
#pragma unroll
        for (int mi = 0; mi < 4; ++mi)
            af[mi] = *reinterpret_cast<const short8*>(
                &As[(mb + mi * 16 + l16) * 32 + quad * 8]);
#pragma unroll
        for (int ni = 0; ni < 4; ++ni)
            bfr[ni] = *reinterpret_cast<const short8*>(
                &Bs[(nbw + ni * 16 + l16) * 32 + quad * 8]);
#pragma unroll
        for (int mi = 0; mi < 4; ++mi)
#pragma unroll
            for (int ni = 0; ni < 4; ++ni)
                acc[mi][ni] = __builtin_amdgcn_mfma_f32_16x16x32_bf16(
                    af[mi], bfr[ni], acc[mi][ni], 0, 0, 0);

        __syncthreads();
    }

#pragma unroll
    for (int mi = 0; mi < 4; ++mi) {
#pragma unroll
        for (int ni = 0; ni < 4; ++ni) {
            const int col = n0 + nbw + ni * 16 + l16;
            const float bsv = bias[col];
#pragma unroll
            for (int r = 0; r < 4; ++r) {
                const int row = m0 + mb + mi * 16 + quad * 4 + r;
                const float v = acc[mi][ni][r] + bsv;
                if (EPI == 0) {
                    const int seg = col >> 10;  // 0=q 1=k 2=v
                    const int c = col & 1023;
                    if (seg == 0) {
                        qws[(size_t)row * 1024 + c] = __float2bfloat16(v);
                    } else {
                        const int b = row >> 10, s = row & 1023;
                        const int h = c >> 6, d = c & 63;
                        const size_t idx =
                            ((size_t)((b * 16 + h) * 1024 + s)) * 64 + d;
                        if (seg == 1) present[idx] = v;
                        else          present[HEAD_ELEMS + idx] = v;
                    }
                } else {
                    outf[(size_t)row * N + col] = v;
                }
            }
        }
    }
}

// ---------------------------------------------------------------------------
// Repack present (fp32 [2][64][1024][64]) into bf16 tiles for attention:
//   k_ws : per (bh,kt) [64 key][64 d],   16B-chunk swizzled: seg ^= (key&7)
//   vt_ws: per (bh,kt) [64 d][64 key],   16B-chunk swizzled: seg ^= (d&7)
// Swizzle makes the attn kernel's ds_read_b128 fragment reads conflict-free
// while keeping the LDS destination linear (required by global_load_lds).
// ---------------------------------------------------------------------------
__global__ __launch_bounds__(256) void repack_kv(
    const float* __restrict__ present,
    __hip_bfloat16* __restrict__ k_ws,
    __hip_bfloat16* __restrict__ vt_ws)
{
    const int kt = blockIdx.x;   // 16 tiles
    const int bh = blockIdx.y;   // 64 heads
    const int tid = threadIdx.x;
    const size_t toff = ((size_t)bh * 1024 + kt * 64) * 64;
    const float* Kp = present + toff;
    const float* Vp = present + HEAD_ELEMS + toff;
    __hip_bfloat16* ko = k_ws  + ((size_t)bh * 16 + kt) * 4096;
    __hip_bfloat16* vo = vt_ws + ((size_t)bh * 16 + kt) * 4096;

    __shared__ float Vt[64][65];

    const int row = tid >> 3, seg = tid & 7;   // row 0..31, seg 0..7
#pragma unroll
    for (int it = 0; it < 2; ++it) {
        const int r = row + it * 32;
        // K: convert + swizzled store (16B chunk stays contiguous)
        *reinterpret_cast<uint4*>(&ko[r * 64 + ((seg ^ (r & 7)) << 3)]) =
            cvt8(Kp + (size_t)r * 64 + seg * 8);
        // V: into LDS transposed (fp32, pad 65 -> conflict-light)
        const float* vp = Vp + (size_t)r * 64 + seg * 8;
        float4 v0 = *reinterpret_cast<const float4*>(vp);
        float4 v1 = *reinterpret_cast<const float4*>(vp + 4);
        Vt[seg * 8 + 0][r] = v0.x; Vt[seg * 8 + 1][r] = v0.y;
        Vt[seg * 8 + 2][r] = v0.z; Vt[seg * 8 + 3][r] = v0.w;
        Vt[seg * 8 + 4][r] = v1.x; Vt[seg * 8 + 5][r] = v1.y;
        Vt[seg * 8 + 6][r] = v1.z; Vt[seg * 8 + 7][r] = v1.w;
    }
    __syncthreads();
#pragma unroll
    for (int it = 0; it < 2; ++it) {
        const int d = row + it * 32;
        BF8 u;
#pragma unroll
        for (int i = 0; i < 8; ++i)
            u.h[i] = __float2bfloat16(Vt[d][seg * 8 + i]);
        *reinterpret_cast<uint4*>(&vo[d * 64 + ((seg ^ (d & 7)) << 3)]) = u.v;
    }
}

// ---------------------------------------------------------------------------
// Causal flash attention v3. One block per (q-tile, head, batch), heavy tiles
// dispatched first (qt = 15 - bx). K/V read as pre-swizzled bf16 via linear
// global_load_lds (zero staging VALU); fragment reads are conflict-free.
// Output written in-place over q_ws (row/col ranges disjoint across blocks;
// q is register-resident before any write).
// ---------------------------------------------------------------------------
__global__ __launch_bounds__(256) void attn_v3(
    const __hip_bfloat16* __restrict__ q_ws,
    const __hip_bfloat16* __restrict__ k_ws,
    const __hip_bfloat16* __restrict__ vt_ws,
    __hip_bfloat16* __restrict__ a_ws)
{
    const int qt = 15 - blockIdx.x, h = blockIdx.y, b = blockIdx.z;
    const int tid  = threadIdx.x;
    const int wave = tid >> 6, lane = tid & 63;
    const int quad = lane >> 4, l16 = lane & 15;
    const int stripe = wave * 16;                 // wave's 16 q-rows

    const int bh = b * 16 + h;
    const __hip_bfloat16* Kbase = k_ws  + (size_t)bh * 16 * 4096;
    const __hip_bfloat16* Vbase = vt_ws + (size_t)bh * 16 * 4096;

    __shared__ __align__(16) __hip_bfloat16 Ksf[4096];   // [key][d] swizzled
    __shared__ __align__(16) __hip_bfloat16 Vsf[4096];   // [d][key] swizzled
    __shared__ __align__(16) __hip_bfloat16 Ps[64][72];  // [q][key]

    // Q fragments in registers: rows stripe+l16, k = quad*8 (+32)
    const __hip_bfloat16* Qb =
        q_ws + ((size_t)(b * Ssz + qt * 64 + stripe + l16)) * NXc + h * 64;
    const short8 qf0 = *reinterpret_cast<const short8*>(Qb + quad * 8);
    const short8 qf1 = *reinterpret_cast<const short8*>(Qb + 32 + quad * 8);

    float m_i[4], l_i[4];
#pragma unroll
    for (int r = 0; r < 4; ++r) { m_i[r] = -1e9f; l_i[r] = 0.f; }
    floatx4 oacc[4];
#pragma unroll
    for (int ni = 0; ni < 4; ++ni)
#pragma unroll
        for (int r = 0; r < 4; ++r) oacc[ni][r] = 0.f;

    for (int kt = 0; kt <= qt; ++kt) {
        // ---- stage K,V: pure async linear copies (4 x 1KB per wave) ----
        const __hip_bfloat16* Kt = Kbase + kt * 4096;
        const __hip_bfloat16* Vt = Vbase + kt * 4096;
#pragma unroll
        for (int c2 = 0; c2 < 2; ++c2) {
            const int c = wave + c2 * 4;               // wave-uniform chunk
            load_lds_16B(Kt + c * 512 + (lane << 3), &Ksf[c * 512]);
            load_lds_16B(Vt + c * 512 + (lane << 3), &Vsf[c * 512]);
        }
        __syncthreads();

        // ---- S = Q K^T : wave's 16 rows x 64 keys ----
        floatx4 sacc[4];
#pragma unroll
        for (int ni = 0; ni < 4; ++ni)
#pragma unroll
            for (int r = 0; r < 4; ++r) sacc[ni][r] = 0.f;
#pragma unroll
        for (int ni = 0; ni < 4; ++ni) {
            const int key = ni * 16 + l16;
            const int sw = key & 7;
            const short8 kf0 = *reinterpret_cast<const short8*>(
                &Ksf[key * 64 + ((quad ^ sw) << 3)]);
            const short8 kf1 = *reinterpret_cast<const short8*>(
                &Ksf[key * 64 + (((4 + quad) ^ sw) << 3)]);
            sacc[ni] = __builtin_amdgcn_mfma_f32_16x16x32_bf16(
                qf0, kf0, sacc[ni], 0, 0, 0);
            sacc[ni] = __builtin_amdgcn_mfma_f32_16x16x32_bf16(
                qf1, kf1, sacc[ni], 0, 0, 0);
        }

        // ---- in-register online softmax (per lane: 4 rows) ----
        const bool diag = (kt == qt);
        float alpha_[4];
#pragma unroll
        for (int r = 0; r < 4; ++r) {
            const int lrow = stripe + quad * 4 + r;
            float sv[4];
            float mx = -1e30f;
#pragma unroll
            for (int ni = 0; ni < 4; ++ni) {
                float v = sacc[ni][r] * 0.125f;     // 1/sqrt(64)
                if (diag && (ni * 16 + l16) > lrow) v = -1e9f;
                sv[ni] = v;
                mx = fmaxf(mx, v);
            }
            mx = fmaxf(mx, __shfl_xor(mx, 1));
            mx = fmaxf(mx, __shfl_xor(mx, 2));
            mx = fmaxf(mx, __shfl_xor(mx, 4));
            mx = fmaxf(mx, __shfl_xor(mx, 8));
            const float mnew = fmaxf(m_i[r], mx);
            const float al = __expf(m_i[r] - mnew);
            m_i[r] = mnew;
            float s = 0.f;
#pragma unroll
            for (int nn = 0; nn < 4; ++nn) {
                const int ni = (nn + quad) & 3;     // bank-rotated stores
                const float p = __expf(sv[ni] - mnew);
                s += p;
                Ps[lrow][ni * 16 + l16] = __float2bfloat16(p);
            }
            s += __shfl_xor(s, 1);
            s += __shfl_xor(s, 2);
            s += __shfl_xor(s, 4);
            s += __shfl_xor(s, 8);
            l_i[r] = l_i[r] * al + s;
            alpha_[r] = al;
        }

        // rescale O (registers only)
#pragma unroll
        for (int ni = 0; ni < 4; ++ni)
#pragma unroll
            for (int r = 0; r < 4; ++r) oacc[ni][r] *= alpha_[r];

        // ---- O += P V : Ps rows written+read by this wave (no barrier) ----
#pragma unroll
        for (int kk = 0; kk < 64; kk += 32) {
            const short8 pf = *reinterpret_cast<const short8*>(
                &Ps[stripe + l16][kk + quad * 8]);
#pragma unroll
            for (int ni = 0; ni < 4; ++ni) {
                const int d = ni * 16 + l16;
                const int chunk = (kk >> 3) + quad;
                const short8 vf = *reinterpret_cast<const short8*>(
                    &Vsf[d * 64 + ((chunk ^ (d & 7)) << 3)]);
                oacc[ni] = __builtin_amdgcn_mfma_f32_16x16x32_bf16(
                    pf, vf, oacc[ni], 0, 0, 0);
            }
        }
        __syncthreads();   // protect Ksf/Vsf before next staging
    }

    // ---- epilogue: O / l -> a_ws (in-place over q_ws) ----
#pragma unroll
    for (int ni = 0; ni < 4; ++ni) {
#pragma unroll
        for (int r = 0; r < 4; ++r) {
            const int row = qt * 64 + stripe + quad * 4 + r;
            const int col = h * 64 + ni * 16 + l16;
            const float inv = 1.0f / fmaxf(l_i[r], 1e-20f);
            a_ws[((size_t)(b * Ssz + row)) * NXc + col] =
                __float2bfloat16(oacc[ni][r] * inv);
        }
    }
}

// ===========================================================================
// FALLBACK PATH (round-3, known-passing; used if ws_size < 32 MB)
// ===========================================================================
template <int EPI>
__global__ __launch_bounds__(256) void gemm64(
    const void* __restrict__ Av, const float* __restrict__ Bw,
    const float* __restrict__ bias, float* __restrict__ out0,
    float* __restrict__ present, int M, int N, int K)
{
    __shared__ __align__(16) __hip_bfloat16 As[64][40];
    __shared__ __align__(16) __hip_bfloat16 Bs[64][40];
    const int tid = threadIdx.x;
    const int wave = tid >> 6, lane = tid & 63;
    const int quad = lane >> 4, l16 = lane & 15;
    const int m0 = blockIdx.y * 64, n0 = blockIdx.x * 64;
    const int mb = (wave >> 1) * 32, nb = (wave & 1) * 32;
    const int arow = tid >> 2, aseg = tid & 3;
    const int brow = tid >> 3, bseg = tid & 7;
    floatx4 acc[2][2];
#pragma unroll
    for (int i = 0; i < 2; ++i)
#pragma unroll
        for (int j = 0; j < 2; ++j)
#pragma unroll
            for (int r = 0; r < 4; ++r) acc[i][j][r] = 0.f;
    for (int k0 = 0; k0 < K; k0 += 32) {
        if (EPI == 0) {
            const float* A = (const float*)Av;
            *reinterpret_cast<uint4*>(&As[arow][aseg * 8]) =
                cvt8(A + (size_t)(m0 + arow) * K + k0 + aseg * 8);
        } else {
            const __hip_bfloat16* A = (const __hip_bfloat16*)Av;
            *reinterpret_cast<uint4*>(&As[arow][aseg * 8]) =
                *reinterpret_cast<const uint4*>(
                    A + (size_t)(m0 + arow) * K + k0 + aseg * 8);
        }
        const float* bp = Bw + (size_t)(k0 + brow) * N + n0 + bseg * 8;
        float4 b0 = *reinterpret_cast<const float4*>(bp);
        float4 b1 = *reinterpret_cast<const float4*>(bp + 4);
        Bs[bseg * 8 + 0][brow] = __float2bfloat16(b0.x);
        Bs[bseg * 8 + 1][brow] = __float2bfloat16(b0.y);
        Bs[bseg * 8 + 2][brow] = __float2bfloat16(b0.z);
        Bs[bseg * 8 + 3][brow] = __float2bfloat16(b0.w);
        Bs[bseg * 8 + 4][brow] = __float2bfloat16(b1.x);
        Bs[bseg * 8 + 5][brow] = __float2bfloat16(b1.y);
        Bs[bseg * 8 + 6][brow] = __float2bfloat16(b1.z);
        Bs[bseg * 8 + 7][brow] = __float2bfloat16(b1.w);
        __syncthreads();
        short8 af[2], bf[2];
#pragma unroll
        for (int mm = 0; mm < 2; ++mm)
            af[mm] = *reinterpret_cast<const short8*>(&As[mb + mm * 16 + l16][quad * 8]);
#pragma unroll
        for (int nn = 0; nn < 2; ++nn)
            bf[nn] = *reinterpret_cast<const short8*>(&Bs[nb + nn * 16 + l16][quad * 8]);
#pragma unroll
        for (int mm = 0; mm < 2; ++mm)
#pragma unroll
            for (int nn = 0; nn < 2; ++nn)
                acc[mm][nn] = __builtin_amdgcn_mfma_f32_16x16x32_bf16(
                    af[mm], bf[nn], acc[mm][nn], 0, 0, 0);
        __syncthreads();
    }
#pragma unroll
    for (int mm = 0; mm < 2; ++mm)
#pragma unroll
        for (int nn = 0; nn < 2; ++nn) {
            const int col = n0 + nb + nn * 16 + l16;
            const float bsv = bias[col];
#pragma unroll
            for (int r = 0; r < 4; ++r) {
                const int row = m0 + mb + mm * 16 + quad * 4 + r;
                const float v = acc[mm][nn][r] + bsv;
                if (EPI == 0) {
                    const int seg = col >> 10;
                    const int c = col & 1023;
                    if (seg == 0) out0[(size_t)row * 1024 + c] = v;
                    else {
                        const int b = row >> 10, s = row & 1023;
                        const int h = c >> 6, d = c & 63;
                        const size_t idx = ((size_t)((b * 16 + h) * 1024 + s)) * 64 + d;
                        if (seg == 1) present[idx] = v;
                        else          present[HEAD_ELEMS + idx] = v;
                    }
                } else out0[(size_t)row * N + col] = v;
            }
        }
}

__global__ __launch_bounds__(256) void attn64(
    const float* __restrict__ qbuf, const float* __restrict__ present,
    __hip_bfloat16* __restrict__ a_ws)
{
    const int qt = blockIdx.x, h = blockIdx.y, b = blockIdx.z;
    const int tid = threadIdx.x;
    const int wave = tid >> 6, lane = tid & 63;
    const int quad = lane >> 4, l16 = lane & 15;
    const int mb = (wave >> 1) * 32, nb = (wave & 1) * 32;
    const size_t headoff = ((size_t)(b * 16 + h)) * Ssz * HDc;
    const float* Qb = qbuf + ((size_t)(b * Ssz + qt * 64)) * NXc + h * 64;
    const float* Kp = present + headoff;
    const float* Vp = present + HEAD_ELEMS + headoff;
    __shared__ __align__(16) __hip_bfloat16 Qs[64][72];
    __shared__ __align__(16) __hip_bfloat16 Ks[64][72];
    __shared__ __align__(16) __hip_bfloat16 Vts[64][72];
    __shared__ __align__(16) __hip_bfloat16 Ps[64][72];
    __shared__ float Sc[64][65];
    __shared__ float mrow[64], lrow[64], arw[64];
#pragma unroll
    for (int it = 0; it < 2; ++it) {
        const int c = tid + it * 256;
        const int row = c >> 3, seg = c & 7;
        *reinterpret_cast<uint4*>(&Qs[row][seg * 8]) =
            cvt8(Qb + (size_t)row * NXc + seg * 8);
    }
    if (tid < 64) { mrow[tid] = -1e9f; lrow[tid] = 0.f; }
    floatx4 oacc[2][2];
#pragma unroll
    for (int i = 0; i < 2; ++i)
#pragma unroll
        for (int j = 0; j < 2; ++j)
#pragma unroll
            for (int r = 0; r < 4; ++r) oacc[i][j][r] = 0.f;
    __syncthreads();
    for (int kt = 0; kt <= qt; ++kt) {
#pragma unroll
        for (int it = 0; it < 2; ++it) {
            const int c = tid + it * 256;
            const int row = c >> 3, seg = c & 7;
            *reinterpret_cast<uint4*>(&Ks[row][seg * 8]) =
                cvt8(Kp + (size_t)(kt * 64 + row) * 64 + seg * 8);
            const float* vp = Vp + (size_t)(kt * 64 + row) * 64 + seg * 8;
            float4 v0 = *reinterpret_cast<const float4*>(vp);
            float4 v1 = *reinterpret_cast<const float4*>(vp + 4);
            Vts[seg * 8 + 0][row] = __float2bfloat16(v0.x);
            Vts[seg * 8 + 1][row] = __float2bfloat16(v0.y);
            Vts[seg * 8 + 2][row] = __float2bfloat16(v0.z);
            Vts[seg * 8 + 3][row] = __float2bfloat16(v0.w);
            Vts[seg * 8 + 4][row] = __float2bfloat16(v1.x);
            Vts[seg * 8 + 5][row] = __float2bfloat16(v1.y);
            Vts[seg * 8 + 6][row] = __float2bfloat16(v1.z);
            Vts[seg * 8 + 7][row] = __float2bfloat16(v1.w);
        }
        __syncthreads();
        floatx4 sacc[2][2];
#pragma unroll
        for (int i = 0; i < 2; ++i)
#pragma unroll
            for (int j = 0; j < 2; ++j)
#pragma unroll
                for (int r = 0; r < 4; ++r) sacc[i][j][r] = 0.f;
#pragma unroll
        for (int kd = 0; kd < 64; kd += 32) {
            short8 af[2], bf[2];
#pragma unroll
            for (int mm = 0; mm < 2; ++mm)
                af[mm] = *reinterpret_cast<const short8*>(&Qs[mb + mm * 16 + l16][kd + quad * 8]);
#pragma unroll
            for (int nn = 0; nn < 2; ++nn)
                bf[nn] = *reinterpret_cast<const short8*>(&Ks[nb + nn * 16 + l16][kd + quad * 8]);
#pragma unroll
            for (int mm = 0; mm < 2; ++mm)
#pragma unroll
                for (int nn = 0; nn < 2; ++nn)
                    sacc[mm][nn] = __builtin_amdgcn_mfma_f32_16x16x32_bf16(
                        af[mm], bf[nn], sacc[mm][nn], 0, 0, 0);
        }
        const bool diag = (kt == qt);
#pragma unroll
        for (int mm = 0; mm < 2; ++mm)
#pragma unroll
            for (int nn = 0; nn < 2; ++nn)
#pragma unroll
                for (int r = 0; r < 4; ++r) {
                    const int row = mb + mm * 16 + quad * 4 + r;
                    const int col = nb + nn * 16 + l16;
                    float v = fminf(fmaxf(sacc[mm][nn][r] * 0.125f, -1e8f), 1e8f);
                    if (diag && col > row) v = -1e9f;
                    Sc[row][col] = v;
                }
        __syncthreads();
        if (tid < 64) {
            const int r = tid;
            const float mo = mrow[r];
            float mx = mo;
            for (int c = 0; c < 64; ++c) mx = fmaxf(mx, Sc[r][c]);
            const float al = (mo <= -5e8f) ? 0.f : __expf(mo - mx);
            float sum = 0.f;
            for (int c = 0; c < 64; ++c) {
                const float sv = Sc[r][c];
                const float p = (sv <= -5e8f) ? 0.f : __expf(sv - mx);
                sum += p;
                Ps[r][c] = __float2bfloat16(p);
            }
            mrow[r] = mx;
            lrow[r] = lrow[r] * al + sum;
            arw[r]  = al;
        }
        __syncthreads();
#pragma unroll
        for (int mm = 0; mm < 2; ++mm) {
            const int rbase = mb + mm * 16 + quad * 4;
#pragma unroll
            for (int r = 0; r < 4; ++r) {
                const float al = arw[rbase + r];
                oacc[mm][0][r] *= al;
                oacc[mm][1][r] *= al;
            }
        }
#pragma unroll
        for (int kk = 0; kk < 64; kk += 32) {
            short8 pf[2], vf[2];
#pragma unroll
            for (int mm = 0; mm < 2; ++mm)
                pf[mm] = *reinterpret_cast<const short8*>(&Ps[mb + mm * 16 + l16][kk + quad * 8]);
#pragma unroll
            for (int nn = 0; nn < 2; ++nn)
                vf[nn] = *reinterpret_cast<const short8*>(&Vts[nb + nn * 16 + l16][kk + quad * 8]);
#pragma unroll
            for (int mm = 0; mm < 2; ++mm)
#pragma unroll
                for (int nn = 0; nn < 2; ++nn)
                    oacc[mm][nn] = __builtin_amdgcn_mfma_f32_16x16x32_bf16(
                        pf[mm], vf[nn], oacc[mm][nn], 0, 0, 0);
        }
        __syncthreads();
    }
#pragma unroll
    for (int mm = 0; mm < 2; ++mm)
#pragma unroll
        for (int nn = 0; nn < 2; ++nn)
#pragma unroll
            for (int r = 0; r < 4; ++r) {
                const int row = mb + mm * 16 + quad * 4 + r;
                const int col = nb + nn * 16 + l16;
                const float inv = 1.0f / fmaxf(lrow[row], 1e-20f);
                a_ws[((size_t)(b * Ssz + qt * 64 + row)) * NXc + h * 64 + col] =
                    __float2bfloat16(oacc[mm][nn][r] * inv);
            }
}

// ===========================================================================
extern "C" void kernel_launch(void* const* d_in, const int* in_sizes, int n_in,
                              void* d_out, int out_size, void* d_ws, size_t ws_size,
                              hipStream_t stream) {
    const float* x      = (const float*)d_in[0];
    const float* w_attn = (const float*)d_in[1];
    const float* b_attn = (const float*)d_in[2];
    const float* w_proj = (const float*)d_in[3];
    const float* b_proj = (const float*)d_in[4];

    float* out     = (float*)d_out;
    float* present = out + OUT_ELEMS;

    const size_t NEED = 32u * 1024u * 1024u;
    if (ws_size >= NEED) {
        // ws layout (bf16 elems), 32 MB total with region reuse:
        //   reg1 [0,4M)   : x_bf (phases 1-2), then vt_ws (phases 2.5-3)
        //   reg2 [4M,8M)  : q_ws (phases 2-3), then a_ws in-place (3-4)
        //   reg3 [8M,12M) : k_ws (phases 2.5-3)
        //   wTa  [12M,15M): transposed w_attn (phases 1-2)
        //   wTp  [15M,16M): transposed w_proj (phases 1-4)
        __hip_bfloat16* reg1 = (__hip_bfloat16*)d_ws;
        __hip_bfloat16* reg2 = reg1 + 4194304;
        __hip_bfloat16* reg3 = reg2 + 4194304;
        __hip_bfloat16* wTa  = reg3 + 4194304;
        __hip_bfloat16* wTp  = wTa + 3145728;

        cvt_kernel<<<2048, 256, 0, stream>>>(x, reg1, OUT_ELEMS);
        transpose_cvt<<<dim3(48, 16), 256, 0, stream>>>(w_attn, wTa, 1024, 3072);
        transpose_cvt<<<dim3(16, 16), 256, 0, stream>>>(w_proj, wTp, 1024, 1024);

        gemm128<0><<<dim3(24, 32), 256, 0, stream>>>(
            reg1, wTa, b_attn, nullptr, reg2, present, 4096, 3072, 1024);

        repack_kv<<<dim3(16, 64), 256, 0, stream>>>(present, reg3, reg1);

        attn_v3<<<dim3(16, 16, 4), 256, 0, stream>>>(reg2, reg3, reg1, reg2);

        gemm128<1><<<dim3(8, 32), 256, 0, stream>>>(
            reg2, wTp, b_proj, out, nullptr, nullptr, 4096, 1024, 1024);
    } else {
        // round-3 fallback (needs 8 MB ws)
        __hip_bfloat16* a_ws = (__hip_bfloat16*)d_ws;
        hipMemsetAsync(d_ws, 0, (size_t)OUT_ELEMS * sizeof(__hip_bfloat16), stream);
        gemm64<0><<<dim3(48, 64), 256, 0, stream>>>(x, w_attn, b_attn, out, present,
                                                    4096, 3072, 1024);
        attn64<<<dim3(16, 16, 4), 256, 0, stream>>>(out, present, a_ws);
        gemm64<1><<<dim3(16, 64), 256, 0, stream>>>(a_ws, w_proj, b_proj, out, nullptr,
                                                    4096, 1024, 1024);
    }
}

// Round 2
// 213.932 us; speedup vs baseline: 1.1417x; 1.1417x over previous
//
#include <hip/hip_runtime.h>
#include <hip/hip_bf16.h>

typedef __attribute__((ext_vector_type(8))) short short8;
typedef __attribute__((ext_vector_type(4))) float floatx4;

constexpr int Bsz = 4, Ssz = 1024, NXc = 1024, NHc = 16, HDc = 64;
constexpr int OUT_ELEMS  = Bsz * Ssz * NXc;        // 4194304
constexpr int HEAD_ELEMS = Bsz * NHc * Ssz * HDc;  // 4194304

union BF8 { __hip_bfloat16 h[8]; uint4 v; short8 s; };

__device__ __forceinline__ uint4 cvt8(const float* __restrict__ p) {
    float4 a = *reinterpret_cast<const float4*>(p);
    float4 b = *reinterpret_cast<const float4*>(p + 4);
    BF8 u;
    u.h[0] = __float2bfloat16(a.x); u.h[1] = __float2bfloat16(a.y);
    u.h[2] = __float2bfloat16(a.z); u.h[3] = __float2bfloat16(a.w);
    u.h[4] = __float2bfloat16(b.x); u.h[5] = __float2bfloat16(b.y);
    u.h[6] = __float2bfloat16(b.z); u.h[7] = __float2bfloat16(b.w);
    return u.v;
}

// async 16B global -> LDS (wave-uniform LDS base + lane*16)
__device__ __forceinline__ void load_lds_16B(const void* g, void* l) {
    __builtin_amdgcn_global_load_lds(
        (const __attribute__((address_space(1))) unsigned int*)g,
        (__attribute__((address_space(3))) unsigned int*)l, 16, 0, 0);
}

// ===========================================================================
// FAST PATH
// ===========================================================================

__global__ __launch_bounds__(256) void cvt_kernel(
    const float* __restrict__ in, __hip_bfloat16* __restrict__ out, int n)
{
    int i = (blockIdx.x * 256 + threadIdx.x) * 8;
    if (i < n)
        *reinterpret_cast<uint4*>(out + i) = cvt8(in + i);
}

// K x N fp32  ->  N x K bf16 (transpose + convert), 64x64 tiles
__global__ __launch_bounds__(256) void transpose_cvt(
    const float* __restrict__ in, __hip_bfloat16* __restrict__ out,
    int K, int N)
{
    __shared__ float t[64][65];
    const int tid = threadIdx.x;
    const int k0 = blockIdx.y * 64, n0 = blockIdx.x * 64;
#pragma unroll
    for (int j = 0; j < 16; ++j) {
        const int idx = tid + j * 256;
        const int row = idx >> 6, col = idx & 63;
        t[row][col] = in[(size_t)(k0 + row) * N + n0 + col];
    }
    __syncthreads();
#pragma unroll
    for (int j = 0; j < 16; ++j) {
        const int idx = tid + j * 256;
        const int orow = idx >> 6, ocol = idx & 63;
        out[(size_t)(n0 + orow) * K + k0 + ocol] = __float2bfloat16(t[ocol][orow]);
    }
}

// ---------------------------------------------------------------------------
// 128x128-tile bf16 GEMM, BK=32, global_load_lds staging (m97 structure).
// ---------------------------------------------------------------------------
template <int EPI>
__global__ __launch_bounds__(256) void gemm128(
    const __hip_bfloat16* __restrict__ A,
    const __hip_bfloat16* __restrict__ Bt,
    const float* __restrict__ bias,
    float* __restrict__ outf,
    __hip_bfloat16* __restrict__ qws,
    float* __restrict__ present,
    int M, int N, int K)
{
    __shared__ __align__(16) __hip_bfloat16 As[128 * 32];
    __shared__ __align__(16) __hip_bfloat16 Bs[128 * 32];

    const int tid  = threadIdx.x;
    const int w    = tid >> 6, lane = tid & 63;
    const int quad = lane >> 4, l16 = lane & 15;
    const int m0 = blockIdx.y * 128, n0 = blockIdx.x * 128;
    const int mb = (w >> 1) * 64, nbw = (w & 1) * 64;

    const int srow = lane >> 2;
    const int skseg = (lane & 3) * 8;

    floatx4 acc[4][4];
#pragma unroll
    for (int i = 0; i < 4; ++i)
#pragma unroll
        for (int j = 0; j < 4; ++j)
#pragma unroll
            for (int r = 0; r < 4; ++r) acc[i][j][r] = 0.f;

    for (int k0 = 0; k0 < K; k0 += 32) {
#pragma unroll
        for (int c = 0; c < 2; ++c) {
            const int chunk = w * 2 + c;
            const int row = chunk * 16 + srow;
            load_lds_16B(A + (size_t)(m0 + row) * K + k0 + skseg,
                         &As[chunk * 512]);
            load_lds_16B(Bt + (size_t)(n0 + row) * K + k0 + skseg,
                         &Bs[chunk * 512]);
        }
        __syncthreads();

        short8 af[4], bfr[4];
#pragma unroll
        for (int mi = 0; mi < 4; ++mi)
            af[mi] = *reinterpret_cast<const short8*>(
                &As[(mb + mi * 16 + l16) * 32 + quad * 8]);
#pragma unroll
        for (int ni = 0; ni < 4; ++ni)
            bfr[ni] = *reinterpret_cast<const short8*>(
                &Bs[(nbw + ni * 16 + l16) * 32 + quad * 8]);
#pragma unroll
        for (int mi = 0; mi < 4; ++mi)
#pragma unroll
            for (int ni = 0; ni < 4; ++ni)
                acc[mi][ni] = __builtin_amdgcn_mfma_f32_16x16x32_bf16(
                    af[mi], bfr[ni], acc[mi][ni], 0, 0, 0);

        __syncthreads();
    }

#pragma unroll
    for (int mi = 0; mi < 4; ++mi) {
#pragma unroll
        for (int ni = 0; ni < 4; ++ni) {
            const int col = n0 + nbw + ni * 16 + l16;
            const float bsv = bias[col];
#pragma unroll
            for (int r = 0; r < 4; ++r) {
                const int row = m0 + mb + mi * 16 + quad * 4 + r;
                const float v = acc[mi][ni][r] + bsv;
                if (EPI == 0) {
                    const int seg = col >> 10;  // 0=q 1=k 2=v
                    const int c = col & 1023;
                    if (seg == 0) {
                        qws[(size_t)row * 1024 + c] = __float2bfloat16(v);
                    } else {
                        const int b = row >> 10, s = row & 1023;
                        const int h = c >> 6, d = c & 63;
                        const size_t idx =
                            ((size_t)((b * 16 + h) * 1024 + s)) * 64 + d;
                        if (seg == 1) present[idx] = v;
                        else          present[HEAD_ELEMS + idx] = v;
                    }
                } else {
                    outf[(size_t)row * N + col] = v;
                }
            }
        }
    }
}

// ---------------------------------------------------------------------------
// Repack present (fp32 [2][64][1024][64]) into bf16 tiles for attention:
//   k_ws : per (bh,kt) [64 key][64 d],   16B-chunk swizzled: seg ^= (key&7)
//   vt_ws: per (bh,kt) [64 d][64 key],   16B-chunk swizzled: seg ^= (d&7)
// ---------------------------------------------------------------------------
__global__ __launch_bounds__(256) void repack_kv(
    const float* __restrict__ present,
    __hip_bfloat16* __restrict__ k_ws,
    __hip_bfloat16* __restrict__ vt_ws)
{
    const int kt = blockIdx.x;   // 16 tiles
    const int bh = blockIdx.y;   // 64 heads
    const int tid = threadIdx.x;
    const size_t toff = ((size_t)bh * 1024 + kt * 64) * 64;
    const float* Kp = present + toff;
    const float* Vp = present + HEAD_ELEMS + toff;
    __hip_bfloat16* ko = k_ws  + ((size_t)bh * 16 + kt) * 4096;
    __hip_bfloat16* vo = vt_ws + ((size_t)bh * 16 + kt) * 4096;

    __shared__ float Vt[64][65];

    const int row = tid >> 3, seg = tid & 7;   // row 0..31, seg 0..7
#pragma unroll
    for (int it = 0; it < 2; ++it) {
        const int r = row + it * 32;
        // K: convert + swizzled store (16B chunk stays contiguous)
        *reinterpret_cast<uint4*>(&ko[r * 64 + ((seg ^ (r & 7)) << 3)]) =
            cvt8(Kp + (size_t)r * 64 + seg * 8);
        // V: into LDS transposed (fp32, pad 65 -> conflict-light)
        const float* vp = Vp + (size_t)r * 64 + seg * 8;
        float4 v0 = *reinterpret_cast<const float4*>(vp);
        float4 v1 = *reinterpret_cast<const float4*>(vp + 4);
        Vt[seg * 8 + 0][r] = v0.x; Vt[seg * 8 + 1][r] = v0.y;
        Vt[seg * 8 + 2][r] = v0.z; Vt[seg * 8 + 3][r] = v0.w;
        Vt[seg * 8 + 4][r] = v1.x; Vt[seg * 8 + 5][r] = v1.y;
        Vt[seg * 8 + 6][r] = v1.z; Vt[seg * 8 + 7][r] = v1.w;
    }
    __syncthreads();
#pragma unroll
    for (int it = 0; it < 2; ++it) {
        const int d = row + it * 32;
        BF8 u;
#pragma unroll
        for (int i = 0; i < 8; ++i)
            u.h[i] = __float2bfloat16(Vt[d][seg * 8 + i]);
        *reinterpret_cast<uint4*>(&vo[d * 64 + ((seg ^ (d & 7)) << 3)]) = u.v;
    }
}

// ---------------------------------------------------------------------------
// Causal flash attention v4.
//  - 512 blocks, uniform work: block bx handles q-tiles {8+bx, 7-bx}
//    (17 kv-tile iterations per block -> no tail imbalance).
//  - Depth-1 software pipeline, 3 K/V LDS buffers, counted vmcnt(4):
//    next tile's global_load_lds stays in flight across the barrier
//    (T3+T4); ONE raw s_barrier per iteration (3-buffer rotation makes
//    the staged buffer one that was last read 2 iterations ago).
//  - setprio(1) around MFMA clusters (T5).
// ---------------------------------------------------------------------------
__global__ __launch_bounds__(256) void attn_v4(
    const __hip_bfloat16* __restrict__ q_ws,
    const __hip_bfloat16* __restrict__ k_ws,
    const __hip_bfloat16* __restrict__ vt_ws,
    __hip_bfloat16* __restrict__ a_ws)
{
    const int bx = blockIdx.x, h = blockIdx.y, b = blockIdx.z;
    const int tid  = threadIdx.x;
    const int wave = tid >> 6, lane = tid & 63;
    const int quad = lane >> 4, l16 = lane & 15;
    const int stripe = wave * 16;                 // wave's 16 q-rows

    const int bh = b * 16 + h;
    const __hip_bfloat16* Kbase = k_ws  + (size_t)bh * 65536;
    const __hip_bfloat16* Vbase = vt_ws + (size_t)bh * 65536;

    __shared__ __align__(16) __hip_bfloat16 Ksf[3][4096];   // [key][d] swz
    __shared__ __align__(16) __hip_bfloat16 Vsf[3][4096];   // [d][key] swz
    __shared__ __align__(16) __hip_bfloat16 Ps[64][72];     // [q][key]

#pragma unroll
    for (int pass = 0; pass < 2; ++pass) {
        const int qt = (pass == 0) ? (8 + bx) : (7 - bx);

        // Q fragments in registers: rows stripe+l16, k = quad*8 (+32)
        const __hip_bfloat16* Qb =
            q_ws + ((size_t)(b * Ssz + qt * 64 + stripe + l16)) * NXc + h * 64;
        const short8 qf0 = *reinterpret_cast<const short8*>(Qb + quad * 8);
        const short8 qf1 = *reinterpret_cast<const short8*>(Qb + 32 + quad * 8);

        float m_i[4], l_i[4];
#pragma unroll
        for (int r = 0; r < 4; ++r) { m_i[r] = -1e9f; l_i[r] = 0.f; }
        floatx4 oacc[4];
#pragma unroll
        for (int ni = 0; ni < 4; ++ni)
#pragma unroll
            for (int r = 0; r < 4; ++r) oacc[ni][r] = 0.f;

        // ---- prologue: stage tile 0 into buffer 0 ----
#pragma unroll
        for (int c2 = 0; c2 < 2; ++c2) {
            const int c = wave + c2 * 4;
            load_lds_16B(Kbase + c * 512 + (lane << 3), &Ksf[0][c * 512]);
            load_lds_16B(Vbase + c * 512 + (lane << 3), &Vsf[0][c * 512]);
        }

        int cw = 0;
        for (int kt = 0; kt <= qt; ++kt) {
            // ---- issue next tile's loads (stay in flight across barrier) ----
            if (kt < qt) {
                const int nb_ = (cw == 2) ? 0 : cw + 1;
                const __hip_bfloat16* Kt = Kbase + (size_t)(kt + 1) * 4096;
                const __hip_bfloat16* Vt = Vbase + (size_t)(kt + 1) * 4096;
#pragma unroll
                for (int c2 = 0; c2 < 2; ++c2) {
                    const int c = wave + c2 * 4;
                    load_lds_16B(Kt + c * 512 + (lane << 3), &Ksf[nb_][c * 512]);
                    load_lds_16B(Vt + c * 512 + (lane << 3), &Vsf[nb_][c * 512]);
                }
                asm volatile("s_waitcnt vmcnt(4)" ::: "memory");
            } else {
                asm volatile("s_waitcnt vmcnt(0)" ::: "memory");
            }
            __builtin_amdgcn_s_barrier();        // all waves: tile cw landed
            __builtin_amdgcn_sched_barrier(0);

            // ---- S = Q K^T : wave's 16 rows x 64 keys ----
            floatx4 sacc[4];
#pragma unroll
            for (int ni = 0; ni < 4; ++ni)
#pragma unroll
                for (int r = 0; r < 4; ++r) sacc[ni][r] = 0.f;
            __builtin_amdgcn_s_setprio(1);
#pragma unroll
            for (int ni = 0; ni < 4; ++ni) {
                const int key = ni * 16 + l16;
                const int sw = key & 7;
                const short8 kf0 = *reinterpret_cast<const short8*>(
                    &Ksf[cw][key * 64 + ((quad ^ sw) << 3)]);
                const short8 kf1 = *reinterpret_cast<const short8*>(
                    &Ksf[cw][key * 64 + (((4 + quad) ^ sw) << 3)]);
                sacc[ni] = __builtin_amdgcn_mfma_f32_16x16x32_bf16(
                    qf0, kf0, sacc[ni], 0, 0, 0);
                sacc[ni] = __builtin_amdgcn_mfma_f32_16x16x32_bf16(
                    qf1, kf1, sacc[ni], 0, 0, 0);
            }
            __builtin_amdgcn_s_setprio(0);

            // ---- in-register online softmax (per lane: 4 rows) ----
            const bool diag = (kt == qt);
            float alpha_[4];
#pragma unroll
            for (int r = 0; r < 4; ++r) {
                const int lrow = stripe + quad * 4 + r;
                float sv[4];
                float mx = -1e30f;
#pragma unroll
                for (int ni = 0; ni < 4; ++ni) {
                    float v = sacc[ni][r] * 0.125f;     // 1/sqrt(64)
                    if (diag && (ni * 16 + l16) > lrow) v = -1e9f;
                    sv[ni] = v;
                    mx = fmaxf(mx, v);
                }
                mx = fmaxf(mx, __shfl_xor(mx, 1));
                mx = fmaxf(mx, __shfl_xor(mx, 2));
                mx = fmaxf(mx, __shfl_xor(mx, 4));
                mx = fmaxf(mx, __shfl_xor(mx, 8));
                const float mnew = fmaxf(m_i[r], mx);
                const float al = __expf(m_i[r] - mnew);
                m_i[r] = mnew;
                float s = 0.f;
#pragma unroll
                for (int nn = 0; nn < 4; ++nn) {
                    const int ni = (nn + quad) & 3;     // bank-rotated stores
                    const float p = __expf(sv[ni] - mnew);
                    s += p;
                    Ps[lrow][ni * 16 + l16] = __float2bfloat16(p);
                }
                s += __shfl_xor(s, 1);
                s += __shfl_xor(s, 2);
                s += __shfl_xor(s, 4);
                s += __shfl_xor(s, 8);
                l_i[r] = l_i[r] * al + s;
                alpha_[r] = al;
            }

            // rescale O (registers only)
#pragma unroll
            for (int ni = 0; ni < 4; ++ni)
#pragma unroll
                for (int r = 0; r < 4; ++r) oacc[ni][r] *= alpha_[r];

            // ---- O += P V : Ps rows written+read by this wave ----
            __builtin_amdgcn_s_setprio(1);
#pragma unroll
            for (int kk = 0; kk < 64; kk += 32) {
                const short8 pf = *reinterpret_cast<const short8*>(
                    &Ps[stripe + l16][kk + quad * 8]);
#pragma unroll
                for (int ni = 0; ni < 4; ++ni) {
                    const int d = ni * 16 + l16;
                    const int chunk = (kk >> 3) + quad;
                    const short8 vf = *reinterpret_cast<const short8*>(
                        &Vsf[cw][d * 64 + ((chunk ^ (d & 7)) << 3)]);
                    oacc[ni] = __builtin_amdgcn_mfma_f32_16x16x32_bf16(
                        pf, vf, oacc[ni], 0, 0, 0);
                }
            }
            __builtin_amdgcn_s_setprio(0);

            cw = (cw == 2) ? 0 : cw + 1;
        }

        // all waves done reading LDS before next pass's prologue staging
        __builtin_amdgcn_s_barrier();

        // ---- epilogue: O / l -> a_ws ----
#pragma unroll
        for (int ni = 0; ni < 4; ++ni) {
#pragma unroll
            for (int r = 0; r < 4; ++r) {
                const int row = qt * 64 + stripe + quad * 4 + r;
                const int col = h * 64 + ni * 16 + l16;
                const float inv = 1.0f / fmaxf(l_i[r], 1e-20f);
                a_ws[((size_t)(b * Ssz + row)) * NXc + col] =
                    __float2bfloat16(oacc[ni][r] * inv);
            }
        }
    }
}

// ===========================================================================
// FALLBACK PATH (round-3, known-passing; used if ws_size < 32 MB)
// ===========================================================================
template <int EPI>
__global__ __launch_bounds__(256) void gemm64(
    const void* __restrict__ Av, const float* __restrict__ Bw,
    const float* __restrict__ bias, float* __restrict__ out0,
    float* __restrict__ present, int M, int N, int K)
{
    __shared__ __align__(16) __hip_bfloat16 As[64][40];
    __shared__ __align__(16) __hip_bfloat16 Bs[64][40];
    const int tid = threadIdx.x;
    const int wave = tid >> 6, lane = tid & 63;
    const int quad = lane >> 4, l16 = lane & 15;
    const int m0 = blockIdx.y * 64, n0 = blockIdx.x * 64;
    const int mb = (wave >> 1) * 32, nb = (wave & 1) * 32;
    const int arow = tid >> 2, aseg = tid & 3;
    const int brow = tid >> 3, bseg = tid & 7;
    floatx4 acc[2][2];
#pragma unroll
    for (int i = 0; i < 2; ++i)
#pragma unroll
        for (int j = 0; j < 2; ++j)
#pragma unroll
            for (int r = 0; r < 4; ++r) acc[i][j][r] = 0.f;
    for (int k0 = 0; k0 < K; k0 += 32) {
        if (EPI == 0) {
            const float* A = (const float*)Av;
            *reinterpret_cast<uint4*>(&As[arow][aseg * 8]) =
                cvt8(A + (size_t)(m0 + arow) * K + k0 + aseg * 8);
        } else {
            const __hip_bfloat16* A = (const __hip_bfloat16*)Av;
            *reinterpret_cast<uint4*>(&As[arow][aseg * 8]) =
                *reinterpret_cast<const uint4*>(
                    A + (size_t)(m0 + arow) * K + k0 + aseg * 8);
        }
        const float* bp = Bw + (size_t)(k0 + brow) * N + n0 + bseg * 8;
        float4 b0 = *reinterpret_cast<const float4*>(bp);
        float4 b1 = *reinterpret_cast<const float4*>(bp + 4);
        Bs[bseg * 8 + 0][brow] = __float2bfloat16(b0.x);
        Bs[bseg * 8 + 1][brow] = __float2bfloat16(b0.y);
        Bs[bseg * 8 + 2][brow] = __float2bfloat16(b0.z);
        Bs[bseg * 8 + 3][brow] = __float2bfloat16(b0.w);
        Bs[bseg * 8 + 4][brow] = __float2bfloat16(b1.x);
        Bs[bseg * 8 + 5][brow] = __float2bfloat16(b1.y);
        Bs[bseg * 8 + 6][brow] = __float2bfloat16(b1.z);
        Bs[bseg * 8 + 7][brow] = __float2bfloat16(b1.w);
        __syncthreads();
        short8 af[2], bf[2];
#pragma unroll
        for (int mm = 0; mm < 2; ++mm)
            af[mm] = *reinterpret_cast<const short8*>(&As[mb + mm * 16 + l16][quad * 8]);
#pragma unroll
        for (int nn = 0; nn < 2; ++nn)
            bf[nn] = *reinterpret_cast<const short8*>(&Bs[nb + nn * 16 + l16][quad * 8]);
#pragma unroll
        for (int mm = 0; mm < 2; ++mm)
#pragma unroll
            for (int nn = 0; nn < 2; ++nn)
                acc[mm][nn] = __builtin_amdgcn_mfma_f32_16x16x32_bf16(
                    af[mm], bf[nn], acc[mm][nn], 0, 0, 0);
        __syncthreads();
    }
#pragma unroll
    for (int mm = 0; mm < 2; ++mm)
#pragma unroll
        for (int nn = 0; nn < 2; ++nn) {
            const int col = n0 + nb + nn * 16 + l16;
            const float bsv = bias[col];
#pragma unroll
            for (int r = 0; r < 4; ++r) {
                const int row = m0 + mb + mm * 16 + quad * 4 + r;
                const float v = acc[mm][nn][r] + bsv;
                if (EPI == 0) {
                    const int seg = col >> 10;
                    const int c = col & 1023;
                    if (seg == 0) out0[(size_t)row * 1024 + c] = v;
                    else {
                        const int b = row >> 10, s = row & 1023;
                        const int h = c >> 6, d = c & 63;
                        const size_t idx = ((size_t)((b * 16 + h) * 1024 + s)) * 64 + d;
                        if (seg == 1) present[idx] = v;
                        else          present[HEAD_ELEMS + idx] = v;
                    }
                } else out0[(size_t)row * N + col] = v;
            }
        }
}

__global__ __launch_bounds__(256) void attn64(
    const float* __restrict__ qbuf, const float* __restrict__ present,
    __hip_bfloat16* __restrict__ a_ws)
{
    const int qt = blockIdx.x, h = blockIdx.y, b = blockIdx.z;
    const int tid = threadIdx.x;
    const int wave = tid >> 6, lane = tid & 63;
    const int quad = lane >> 4, l16 = lane & 15;
    const int mb = (wave >> 1) * 32, nb = (wave & 1) * 32;
    const size_t headoff = ((size_t)(b * 16 + h)) * Ssz * HDc;
    const float* Qb = qbuf + ((size_t)(b * Ssz + qt * 64)) * NXc + h * 64;
    const float* Kp = present + headoff;
    const float* Vp = present + HEAD_ELEMS + headoff;
    __shared__ __align__(16) __hip_bfloat16 Qs[64][72];
    __shared__ __align__(16) __hip_bfloat16 Ks[64][72];
    __shared__ __align__(16) __hip_bfloat16 Vts[64][72];
    __shared__ __align__(16) __hip_bfloat16 Ps[64][72];
    __shared__ float Sc[64][65];
    __shared__ float mrow[64], lrow[64], arw[64];
#pragma unroll
    for (int it = 0; it < 2; ++it) {
        const int c = tid + it * 256;
        const int row = c >> 3, seg = c & 7;
        *reinterpret_cast<uint4*>(&Qs[row][seg * 8]) =
            cvt8(Qb + (size_t)row * NXc + seg * 8);
    }
    if (tid < 64) { mrow[tid] = -1e9f; lrow[tid] = 0.f; }
    floatx4 oacc[2][2];
#pragma unroll
    for (int i = 0; i < 2; ++i)
#pragma unroll
        for (int j = 0; j < 2; ++j)
#pragma unroll
            for (int r = 0; r < 4; ++r) oacc[i][j][r] = 0.f;
    __syncthreads();
    for (int kt = 0; kt <= qt; ++kt) {
#pragma unroll
        for (int it = 0; it < 2; ++it) {
            const int c = tid + it * 256;
            const int row = c >> 3, seg = c & 7;
            *reinterpret_cast<uint4*>(&Ks[row][seg * 8]) =
                cvt8(Kp + (size_t)(kt * 64 + row) * 64 + seg * 8);
            const float* vp = Vp + (size_t)(kt * 64 + row) * 64 + seg * 8;
            float4 v0 = *reinterpret_cast<const float4*>(vp);
            float4 v1 = *reinterpret_cast<const float4*>(vp + 4);
            Vts[seg * 8 + 0][row] = __float2bfloat16(v0.x);
            Vts[seg * 8 + 1][row] = __float2bfloat16(v0.y);
            Vts[seg * 8 + 2][row] = __float2bfloat16(v0.z);
            Vts[seg * 8 + 3][row] = __float2bfloat16(v0.w);
            Vts[seg * 8 + 4][row] = __float2bfloat16(v1.x);
            Vts[seg * 8 + 5][row] = __float2bfloat16(v1.y);
            Vts[seg * 8 + 6][row] = __float2bfloat16(v1.z);
            Vts[seg * 8 + 7][row] = __float2bfloat16(v1.w);
        }
        __syncthreads();
        floatx4 sacc[2][2];
#pragma unroll
        for (int i = 0; i < 2; ++i)
#pragma unroll
            for (int j = 0; j < 2; ++j)
#pragma unroll
                for (int r = 0; r < 4; ++r) sacc[i][j][r] = 0.f;
#pragma unroll
        for (int kd = 0; kd < 64; kd += 32) {
            short8 af[2], bf[2];
#pragma unroll
            for (int mm = 0; mm < 2; ++mm)
                af[mm] = *reinterpret_cast<const short8*>(&Qs[mb + mm * 16 + l16][kd + quad * 8]);
#pragma unroll
            for (int nn = 0; nn < 2; ++nn)
                bf[nn] = *reinterpret_cast<const short8*>(&Ks[nb + nn * 16 + l16][kd + quad * 8]);
#pragma unroll
            for (int mm = 0; mm < 2; ++mm)
#pragma unroll
                for (int nn = 0; nn < 2; ++nn)
                    sacc[mm][nn] = __builtin_amdgcn_mfma_f32_16x16x32_bf16(
                        af[mm], bf[nn], sacc[mm][nn], 0, 0, 0);
        }
        const bool diag = (kt == qt);
#pragma unroll
        for (int mm = 0; mm < 2; ++mm)
#pragma unroll
            for (int nn = 0; nn < 2; ++nn)
#pragma unroll
                for (int r = 0; r < 4; ++r) {
                    const int row = mb + mm * 16 + quad * 4 + r;
                    const int col = nb + nn * 16 + l16;
                    float v = fminf(fmaxf(sacc[mm][nn][r] * 0.125f, -1e8f), 1e8f);
                    if (diag && col > row) v = -1e9f;
                    Sc[row][col] = v;
                }
        __syncthreads();
        if (tid < 64) {
            const int r = tid;
            const float mo = mrow[r];
            float mx = mo;
            for (int c = 0; c < 64; ++c) mx = fmaxf(mx, Sc[r][c]);
            const float al = (mo <= -5e8f) ? 0.f : __expf(mo - mx);
            float sum = 0.f;
            for (int c = 0; c < 64; ++c) {
                const float sv = Sc[r][c];
                const float p = (sv <= -5e8f) ? 0.f : __expf(sv - mx);
                sum += p;
                Ps[r][c] = __float2bfloat16(p);
            }
            mrow[r] = mx;
            lrow[r] = lrow[r] * al + sum;
            arw[r]  = al;
        }
        __syncthreads();
#pragma unroll
        for (int mm = 0; mm < 2; ++mm) {
            const int rbase = mb + mm * 16 + quad * 4;
#pragma unroll
            for (int r = 0; r < 4; ++r) {
                const float al = arw[rbase + r];
                oacc[mm][0][r] *= al;
                oacc[mm][1][r] *= al;
            }
        }
#pragma unroll
        for (int kk = 0; kk < 64; kk += 32) {
            short8 pf[2], vf[2];
#pragma unroll
            for (int mm = 0; mm < 2; ++mm)
                pf[mm] = *reinterpret_cast<const short8*>(&Ps[mb + mm * 16 + l16][kk + quad * 8]);
#pragma unroll
            for (int nn = 0; nn < 2; ++nn)
                vf[nn] = *reinterpret_cast<const short8*>(&Vts[nb + nn * 16 + l16][kk + quad * 8]);
#pragma unroll
            for (int mm = 0; mm < 2; ++mm)
#pragma unroll
                for (int nn = 0; nn < 2; ++nn)
                    oacc[mm][nn] = __builtin_amdgcn_mfma_f32_16x16x32_bf16(
                        pf[mm], vf[nn], oacc[mm][nn], 0, 0, 0);
        }
        __syncthreads();
    }
#pragma unroll
    for (int mm = 0; mm < 2; ++mm)
#pragma unroll
        for (int nn = 0; nn < 2; ++nn)
#pragma unroll
            for (int r = 0; r < 4; ++r) {
                const int row = mb + mm * 16 + quad * 4 + r;
                const int col = nb + nn * 16 + l16;
                const float inv = 1.0f / fmaxf(lrow[row], 1e-20f);
                a_ws[((size_t)(b * Ssz + qt * 64 + row)) * NXc + h * 64 + col] =
                    __float2bfloat16(oacc[mm][nn][r] * inv);
            }
}

// ===========================================================================
extern "C" void kernel_launch(void* const* d_in, const int* in_sizes, int n_in,
                              void* d_out, int out_size, void* d_ws, size_t ws_size,
                              hipStream_t stream) {
    const float* x      = (const float*)d_in[0];
    const float* w_attn = (const float*)d_in[1];
    const float* b_attn = (const float*)d_in[2];
    const float* w_proj = (const float*)d_in[3];
    const float* b_proj = (const float*)d_in[4];

    float* out     = (float*)d_out;
    float* present = out + OUT_ELEMS;

    const size_t NEED = 32u * 1024u * 1024u;
    if (ws_size >= NEED) {
        // ws layout (bf16 elems), 32 MB total with region reuse:
        //   reg1 [0,4M)   : x_bf (phases 1-2), then vt_ws (phases 2.5-3)
        //   reg2 [4M,8M)  : q_ws (phases 2-3), then a_ws in-place (3-4)
        //   reg3 [8M,12M) : k_ws (phases 2.5-3)
        //   wTa  [12M,15M): transposed w_attn (phases 1-2)
        //   wTp  [15M,16M): transposed w_proj (phases 1-4)
        __hip_bfloat16* reg1 = (__hip_bfloat16*)d_ws;
        __hip_bfloat16* reg2 = reg1 + 4194304;
        __hip_bfloat16* reg3 = reg2 + 4194304;
        __hip_bfloat16* wTa  = reg3 + 4194304;
        __hip_bfloat16* wTp  = wTa + 3145728;

        cvt_kernel<<<2048, 256, 0, stream>>>(x, reg1, OUT_ELEMS);
        transpose_cvt<<<dim3(48, 16), 256, 0, stream>>>(w_attn, wTa, 1024, 3072);
        transpose_cvt<<<dim3(16, 16), 256, 0, stream>>>(w_proj, wTp, 1024, 1024);

        gemm128<0><<<dim3(24, 32), 256, 0, stream>>>(
            reg1, wTa, b_attn, nullptr, reg2, present, 4096, 3072, 1024);

        repack_kv<<<dim3(16, 64), 256, 0, stream>>>(present, reg3, reg1);

        attn_v4<<<dim3(8, 16, 4), 256, 0, stream>>>(reg2, reg3, reg1, reg2);

        gemm128<1><<<dim3(8, 32), 256, 0, stream>>>(
            reg2, wTp, b_proj, out, nullptr, nullptr, 4096, 1024, 1024);
    } else {
        // round-3 fallback (needs 8 MB ws)
        __hip_bfloat16* a_ws = (__hip_bfloat16*)d_ws;
        hipMemsetAsync(d_ws, 0, (size_t)OUT_ELEMS * sizeof(__hip_bfloat16), stream);
        gemm64<0><<<dim3(48, 64), 256, 0, stream>>>(x, w_attn, b_attn, out, present,
                                                    4096, 3072, 1024);
        attn64<<<dim3(16, 16, 4), 256, 0, stream>>>(out, present, a_ws);
        gemm64<1><<<dim3(16, 64), 256, 0, stream>>>(a_ws, w_proj, b_proj, out, nullptr,
                                                    4096, 1024, 1024);
    }
}

// Round 3
// 194.859 us; speedup vs baseline: 1.2535x; 1.0979x over previous
//
#include <hip/hip_runtime.h>
#include <hip/hip_bf16.h>

typedef __attribute__((ext_vector_type(8))) short short8;
typedef __attribute__((ext_vector_type(4))) float floatx4;

constexpr int Bsz = 4, Ssz = 1024, NXc = 1024, NHc = 16, HDc = 64;
constexpr int OUT_ELEMS  = Bsz * Ssz * NXc;        // 4194304
constexpr int HEAD_ELEMS = Bsz * NHc * Ssz * HDc;  // 4194304

union BF8 { __hip_bfloat16 h[8]; uint4 v; short8 s; };

__device__ __forceinline__ uint4 cvt8(const float* __restrict__ p) {
    float4 a = *reinterpret_cast<const float4*>(p);
    float4 b = *reinterpret_cast<const float4*>(p + 4);
    BF8 u;
    u.h[0] = __float2bfloat16(a.x); u.h[1] = __float2bfloat16(a.y);
    u.h[2] = __float2bfloat16(a.z); u.h[3] = __float2bfloat16(a.w);
    u.h[4] = __float2bfloat16(b.x); u.h[5] = __float2bfloat16(b.y);
    u.h[6] = __float2bfloat16(b.z); u.h[7] = __float2bfloat16(b.w);
    return u.v;
}

// async 16B global -> LDS (wave-uniform LDS base + lane*16)
__device__ __forceinline__ void load_lds_16B(const void* g, void* l) {
    __builtin_amdgcn_global_load_lds(
        (const __attribute__((address_space(1))) unsigned int*)g,
        (__attribute__((address_space(3))) unsigned int*)l, 16, 0, 0);
}

// ===========================================================================
// FAST PATH
// ===========================================================================

// Fused prep: x fp32->bf16 (blocks 0..2047), w_attn transpose (2048..2815),
// w_proj transpose (2816..3071). One dispatch instead of three.
__global__ __launch_bounds__(256) void prep_kernel(
    const float* __restrict__ x, __hip_bfloat16* __restrict__ x_bf,
    const float* __restrict__ w_attn, __hip_bfloat16* __restrict__ wTa,
    const float* __restrict__ w_proj, __hip_bfloat16* __restrict__ wTp)
{
    const int bid = blockIdx.x, tid = threadIdx.x;
    __shared__ float t[64][65];
    if (bid < 2048) {
        const int i = (bid * 256 + tid) * 8;   // covers exactly OUT_ELEMS
        *reinterpret_cast<uint4*>(x_bf + i) = cvt8(x + i);
        return;
    }
    const float* in; __hip_bfloat16* outp; int N, bx, by;
    if (bid < 2816) { const int q = bid - 2048; in = w_attn; outp = wTa; N = 3072; bx = q % 48; by = q / 48; }
    else            { const int q = bid - 2816; in = w_proj; outp = wTp; N = 1024; bx = q % 16; by = q / 16; }
    const int k0 = by * 64, n0 = bx * 64;
#pragma unroll
    for (int j = 0; j < 16; ++j) {
        const int idx = tid + j * 256;
        const int row = idx >> 6, col = idx & 63;
        t[row][col] = in[(size_t)(k0 + row) * N + n0 + col];
    }
    __syncthreads();
#pragma unroll
    for (int j = 0; j < 16; ++j) {
        const int idx = tid + j * 256;
        const int orow = idx >> 6, ocol = idx & 63;
        outp[(size_t)(n0 + orow) * 1024 + k0 + ocol] = __float2bfloat16(t[ocol][orow]);
    }
}

// ---------------------------------------------------------------------------
// 128x128-tile bf16 GEMM, BK=32, pipelined (attn_v4 pattern):
//   3 LDS buffers, stage-next -> counted vmcnt(4) -> ONE raw s_barrier per
//   K-step -> MFMA (setprio). Next tile's global_load_lds stays in flight
//   across the barrier.
// EPI==0 epilogue additionally emits the bf16 swizzled K/V tiles for the
// attention kernel (folds the former repack_kv dispatch; values identical:
// same fp32 accumulator converted with the same __float2bfloat16).
// ---------------------------------------------------------------------------
template <int EPI>
__global__ __launch_bounds__(256) void gemm128p(
    const __hip_bfloat16* __restrict__ A,
    const __hip_bfloat16* __restrict__ Bt,
    const float* __restrict__ bias,
    float* __restrict__ outf,
    __hip_bfloat16* __restrict__ qws,
    float* __restrict__ present,
    __hip_bfloat16* __restrict__ kws,
    __hip_bfloat16* __restrict__ vtws,
    int M, int N, int K)
{
    __shared__ __align__(16) __hip_bfloat16 As[3][4096];
    __shared__ __align__(16) __hip_bfloat16 Bs[3][4096];

    const int tid  = threadIdx.x;
    const int w    = tid >> 6, lane = tid & 63;
    const int quad = lane >> 4, l16 = lane & 15;
    const int m0 = blockIdx.y * 128, n0 = blockIdx.x * 128;
    const int mb = (w >> 1) * 64, nbw = (w & 1) * 64;

    const int srow = lane >> 2;
    const int skseg = (lane & 3) * 8;

    floatx4 acc[4][4];
#pragma unroll
    for (int i = 0; i < 4; ++i)
#pragma unroll
        for (int j = 0; j < 4; ++j)
#pragma unroll
            for (int r = 0; r < 4; ++r) acc[i][j][r] = 0.f;

    // stage one 128x32 A-tile and B-tile into buffer `buf` (4 loads/wave)
    auto stage = [&](int buf, int k0) {
#pragma unroll
        for (int c = 0; c < 2; ++c) {
            const int chunk = w * 2 + c;
            const int row = chunk * 16 + srow;
            load_lds_16B(A + (size_t)(m0 + row) * K + k0 + skseg,
                         &As[buf][chunk * 512]);
            load_lds_16B(Bt + (size_t)(n0 + row) * K + k0 + skseg,
                         &Bs[buf][chunk * 512]);
        }
    };

    stage(0, 0);
    int cb = 0;
    for (int k0 = 0; k0 < K; k0 += 32) {
        if (k0 + 32 < K) {
            const int nb_ = (cb == 2) ? 0 : cb + 1;
            stage(nb_, k0 + 32);
            asm volatile("s_waitcnt vmcnt(4)" ::: "memory");
        } else {
            asm volatile("s_waitcnt vmcnt(0)" ::: "memory");
        }
        __builtin_amdgcn_s_barrier();          // tile cb landed (all waves)
        __builtin_amdgcn_sched_barrier(0);

        short8 af[4], bfr[4];
#pragma unroll
        for (int mi = 0; mi < 4; ++mi)
            af[mi] = *reinterpret_cast<const short8*>(
                &As[cb][(mb + mi * 16 + l16) * 32 + quad * 8]);
#pragma unroll
        for (int ni = 0; ni < 4; ++ni)
            bfr[ni] = *reinterpret_cast<const short8*>(
                &Bs[cb][(nbw + ni * 16 + l16) * 32 + quad * 8]);
        __builtin_amdgcn_s_setprio(1);
#pragma unroll
        for (int mi = 0; mi < 4; ++mi)
#pragma unroll
            for (int ni = 0; ni < 4; ++ni)
                acc[mi][ni] = __builtin_amdgcn_mfma_f32_16x16x32_bf16(
                    af[mi], bfr[ni], acc[mi][ni], 0, 0, 0);
        __builtin_amdgcn_s_setprio(0);

        cb = (cb == 2) ? 0 : cb + 1;
    }

#pragma unroll
    for (int mi = 0; mi < 4; ++mi) {
#pragma unroll
        for (int ni = 0; ni < 4; ++ni) {
            const int col = n0 + nbw + ni * 16 + l16;
            const float bsv = bias[col];
#pragma unroll
            for (int r = 0; r < 4; ++r) {
                const int row = m0 + mb + mi * 16 + quad * 4 + r;
                const float v = acc[mi][ni][r] + bsv;
                if (EPI == 0) {
                    const int seg = col >> 10;  // 0=q 1=k 2=v
                    const int c = col & 1023;
                    if (seg == 0) {
                        qws[(size_t)row * 1024 + c] = __float2bfloat16(v);
                    } else {
                        const int bq = row >> 10, s = row & 1023;
                        const int hh = c >> 6, d = c & 63;
                        const size_t idx =
                            ((size_t)((bq * 16 + hh) * 1024 + s)) * 64 + d;
                        const int kt = s >> 6, key = s & 63;
                        const size_t tbase =
                            ((size_t)((bq * 16 + hh) * 16 + kt)) * 4096;
                        if (seg == 1) {
                            present[idx] = v;
                            // k_ws: [key][d], 16B-chunk swizzle seg^=key&7
                            kws[tbase + key * 64 +
                                ((((d >> 3) ^ (key & 7)) << 3) | (d & 7))] =
                                __float2bfloat16(v);
                        } else {
                            present[HEAD_ELEMS + idx] = v;
                            // vt_ws: [d][key], 16B-chunk swizzle seg^=d&7
                            vtws[tbase + d * 64 +
                                ((((key >> 3) ^ (d & 7)) << 3) | (key & 7))] =
                                __float2bfloat16(v);
                        }
                    }
                } else {
                    outf[(size_t)row * N + col] = v;
                }
            }
        }
    }
}

// ---------------------------------------------------------------------------
// Causal flash attention v4 (unchanged from round 2; proven).
// ---------------------------------------------------------------------------
__global__ __launch_bounds__(256) void attn_v4(
    const __hip_bfloat16* __restrict__ q_ws,
    const __hip_bfloat16* __restrict__ k_ws,
    const __hip_bfloat16* __restrict__ vt_ws,
    __hip_bfloat16* __restrict__ a_ws)
{
    const int bx = blockIdx.x, h = blockIdx.y, b = blockIdx.z;
    const int tid  = threadIdx.x;
    const int wave = tid >> 6, lane = tid & 63;
    const int quad = lane >> 4, l16 = lane & 15;
    const int stripe = wave * 16;                 // wave's 16 q-rows

    const int bh = b * 16 + h;
    const __hip_bfloat16* Kbase = k_ws  + (size_t)bh * 65536;
    const __hip_bfloat16* Vbase = vt_ws + (size_t)bh * 65536;

    __shared__ __align__(16) __hip_bfloat16 Ksf[3][4096];   // [key][d] swz
    __shared__ __align__(16) __hip_bfloat16 Vsf[3][4096];   // [d][key] swz
    __shared__ __align__(16) __hip_bfloat16 Ps[64][72];     // [q][key]

#pragma unroll
    for (int pass = 0; pass < 2; ++pass) {
        const int qt = (pass == 0) ? (8 + bx) : (7 - bx);

        // Q fragments in registers: rows stripe+l16, k = quad*8 (+32)
        const __hip_bfloat16* Qb =
            q_ws + ((size_t)(b * Ssz + qt * 64 + stripe + l16)) * NXc + h * 64;
        const short8 qf0 = *reinterpret_cast<const short8*>(Qb + quad * 8);
        const short8 qf1 = *reinterpret_cast<const short8*>(Qb + 32 + quad * 8);

        float m_i[4], l_i[4];
#pragma unroll
        for (int r = 0; r < 4; ++r) { m_i[r] = -1e9f; l_i[r] = 0.f; }
        floatx4 oacc[4];
#pragma unroll
        for (int ni = 0; ni < 4; ++ni)
#pragma unroll
            for (int r = 0; r < 4; ++r) oacc[ni][r] = 0.f;

        // ---- prologue: stage tile 0 into buffer 0 ----
#pragma unroll
        for (int c2 = 0; c2 < 2; ++c2) {
            const int c = wave + c2 * 4;
            load_lds_16B(Kbase + c * 512 + (lane << 3), &Ksf[0][c * 512]);
            load_lds_16B(Vbase + c * 512 + (lane << 3), &Vsf[0][c * 512]);
        }

        int cw = 0;
        for (int kt = 0; kt <= qt; ++kt) {
            // ---- issue next tile's loads (stay in flight across barrier) ----
            if (kt < qt) {
                const int nb_ = (cw == 2) ? 0 : cw + 1;
                const __hip_bfloat16* Kt = Kbase + (size_t)(kt + 1) * 4096;
                const __hip_bfloat16* Vt = Vbase + (size_t)(kt + 1) * 4096;
#pragma unroll
                for (int c2 = 0; c2 < 2; ++c2) {
                    const int c = wave + c2 * 4;
                    load_lds_16B(Kt + c * 512 + (lane << 3), &Ksf[nb_][c * 512]);
                    load_lds_16B(Vt + c * 512 + (lane << 3), &Vsf[nb_][c * 512]);
                }
                asm volatile("s_waitcnt vmcnt(4)" ::: "memory");
            } else {
                asm volatile("s_waitcnt vmcnt(0)" ::: "memory");
            }
            __builtin_amdgcn_s_barrier();        // all waves: tile cw landed
            __builtin_amdgcn_sched_barrier(0);

            // ---- S = Q K^T : wave's 16 rows x 64 keys ----
            floatx4 sacc[4];
#pragma unroll
            for (int ni = 0; ni < 4; ++ni)
#pragma unroll
                for (int r = 0; r < 4; ++r) sacc[ni][r] = 0.f;
            __builtin_amdgcn_s_setprio(1);
#pragma unroll
            for (int ni = 0; ni < 4; ++ni) {
                const int key = ni * 16 + l16;
                const int sw = key & 7;
                const short8 kf0 = *reinterpret_cast<const short8*>(
                    &Ksf[cw][key * 64 + ((quad ^ sw) << 3)]);
                const short8 kf1 = *reinterpret_cast<const short8*>(
                    &Ksf[cw][key * 64 + (((4 + quad) ^ sw) << 3)]);
                sacc[ni] = __builtin_amdgcn_mfma_f32_16x16x32_bf16(
                    qf0, kf0, sacc[ni], 0, 0, 0);
                sacc[ni] = __builtin_amdgcn_mfma_f32_16x16x32_bf16(
                    qf1, kf1, sacc[ni], 0, 0, 0);
            }
            __builtin_amdgcn_s_setprio(0);

            // ---- in-register online softmax (per lane: 4 rows) ----
            const bool diag = (kt == qt);
            float alpha_[4];
#pragma unroll
            for (int r = 0; r < 4; ++r) {
                const int lrow = stripe + quad * 4 + r;
                float sv[4];
                float mx = -1e30f;
#pragma unroll
                for (int ni = 0; ni < 4; ++ni) {
                    float v = sacc[ni][r] * 0.125f;     // 1/sqrt(64)
                    if (diag && (ni * 16 + l16) > lrow) v = -1e9f;
                    sv[ni] = v;
                    mx = fmaxf(mx, v);
                }
                mx = fmaxf(mx, __shfl_xor(mx, 1));
                mx = fmaxf(mx, __shfl_xor(mx, 2));
                mx = fmaxf(mx, __shfl_xor(mx, 4));
                mx = fmaxf(mx, __shfl_xor(mx, 8));
                const float mnew = fmaxf(m_i[r], mx);
                const float al = __expf(m_i[r] - mnew);
                m_i[r] = mnew;
                float s = 0.f;
#pragma unroll
                for (int nn = 0; nn < 4; ++nn) {
                    const int ni = (nn + quad) & 3;     // bank-rotated stores
                    const float p = __expf(sv[ni] - mnew);
                    s += p;
                    Ps[lrow][ni * 16 + l16] = __float2bfloat16(p);
                }
                s += __shfl_xor(s, 1);
                s += __shfl_xor(s, 2);
                s += __shfl_xor(s, 4);
                s += __shfl_xor(s, 8);
                l_i[r] = l_i[r] * al + s;
                alpha_[r] = al;
            }

            // rescale O (registers only)
#pragma unroll
            for (int ni = 0; ni < 4; ++ni)
#pragma unroll
                for (int r = 0; r < 4; ++r) oacc[ni][r] *= alpha_[r];

            // ---- O += P V : Ps rows written+read by this wave ----
            __builtin_amdgcn_s_setprio(1);
#pragma unroll
            for (int kk = 0; kk < 64; kk += 32) {
                const short8 pf = *reinterpret_cast<const short8*>(
                    &Ps[stripe + l16][kk + quad * 8]);
#pragma unroll
                for (int ni = 0; ni < 4; ++ni) {
                    const int d = ni * 16 + l16;
                    const int chunk = (kk >> 3) + quad;
                    const short8 vf = *reinterpret_cast<const short8*>(
                        &Vsf[cw][d * 64 + ((chunk ^ (d & 7)) << 3)]);
                    oacc[ni] = __builtin_amdgcn_mfma_f32_16x16x32_bf16(
                        pf, vf, oacc[ni], 0, 0, 0);
                }
            }
            __builtin_amdgcn_s_setprio(0);

            cw = (cw == 2) ? 0 : cw + 1;
        }

        // all waves done reading LDS before next pass's prologue staging
        __builtin_amdgcn_s_barrier();

        // ---- epilogue: O / l -> a_ws ----
#pragma unroll
        for (int ni = 0; ni < 4; ++ni) {
#pragma unroll
            for (int r = 0; r < 4; ++r) {
                const int row = qt * 64 + stripe + quad * 4 + r;
                const int col = h * 64 + ni * 16 + l16;
                const float inv = 1.0f / fmaxf(l_i[r], 1e-20f);
                a_ws[((size_t)(b * Ssz + row)) * NXc + col] =
                    __float2bfloat16(oacc[ni][r] * inv);
            }
        }
    }
}

// ===========================================================================
// FALLBACK PATH (round-3, known-passing; used if ws_size < 32 MB)
// ===========================================================================
template <int EPI>
__global__ __launch_bounds__(256) void gemm64(
    const void* __restrict__ Av, const float* __restrict__ Bw,
    const float* __restrict__ bias, float* __restrict__ out0,
    float* __restrict__ present, int M, int N, int K)
{
    __shared__ __align__(16) __hip_bfloat16 As[64][40];
    __shared__ __align__(16) __hip_bfloat16 Bs[64][40];
    const int tid = threadIdx.x;
    const int wave = tid >> 6, lane = tid & 63;
    const int quad = lane >> 4, l16 = lane & 15;
    const int m0 = blockIdx.y * 64, n0 = blockIdx.x * 64;
    const int mb = (wave >> 1) * 32, nb = (wave & 1) * 32;
    const int arow = tid >> 2, aseg = tid & 3;
    const int brow = tid >> 3, bseg = tid & 7;
    floatx4 acc[2][2];
#pragma unroll
    for (int i = 0; i < 2; ++i)
#pragma unroll
        for (int j = 0; j < 2; ++j)
#pragma unroll
            for (int r = 0; r < 4; ++r) acc[i][j][r] = 0.f;
    for (int k0 = 0; k0 < K; k0 += 32) {
        if (EPI == 0) {
            const float* A = (const float*)Av;
            *reinterpret_cast<uint4*>(&As[arow][aseg * 8]) =
                cvt8(A + (size_t)(m0 + arow) * K + k0 + aseg * 8);
        } else {
            const __hip_bfloat16* A = (const __hip_bfloat16*)Av;
            *reinterpret_cast<uint4*>(&As[arow][aseg * 8]) =
                *reinterpret_cast<const uint4*>(
                    A + (size_t)(m0 + arow) * K + k0 + aseg * 8);
        }
        const float* bp = Bw + (size_t)(k0 + brow) * N + n0 + bseg * 8;
        float4 b0 = *reinterpret_cast<const float4*>(bp);
        float4 b1 = *reinterpret_cast<const float4*>(bp + 4);
        Bs[bseg * 8 + 0][brow] = __float2bfloat16(b0.x);
        Bs[bseg * 8 + 1][brow] = __float2bfloat16(b0.y);
        Bs[bseg * 8 + 2][brow] = __float2bfloat16(b0.z);
        Bs[bseg * 8 + 3][brow] = __float2bfloat16(b0.w);
        Bs[bseg * 8 + 4][brow] = __float2bfloat16(b1.x);
        Bs[bseg * 8 + 5][brow] = __float2bfloat16(b1.y);
        Bs[bseg * 8 + 6][brow] = __float2bfloat16(b1.z);
        Bs[bseg * 8 + 7][brow] = __float2bfloat16(b1.w);
        __syncthreads();
        short8 af[2], bf[2];
#pragma unroll
        for (int mm = 0; mm < 2; ++mm)
            af[mm] = *reinterpret_cast<const short8*>(&As[mb + mm * 16 + l16][quad * 8]);
#pragma unroll
        for (int nn = 0; nn < 2; ++nn)
            bf[nn] = *reinterpret_cast<const short8*>(&Bs[nb + nn * 16 + l16][quad * 8]);
#pragma unroll
        for (int mm = 0; mm < 2; ++mm)
#pragma unroll
            for (int nn = 0; nn < 2; ++nn)
                acc[mm][nn] = __builtin_amdgcn_mfma_f32_16x16x32_bf16(
                    af[mm], bf[nn], acc[mm][nn], 0, 0, 0);
        __syncthreads();
    }
#pragma unroll
    for (int mm = 0; mm < 2; ++mm)
#pragma unroll
        for (int nn = 0; nn < 2; ++nn) {
            const int col = n0 + nb + nn * 16 + l16;
            const float bsv = bias[col];
#pragma unroll
            for (int r = 0; r < 4; ++r) {
                const int row = m0 + mb + mm * 16 + quad * 4 + r;
                const float v = acc[mm][nn][r] + bsv;
                if (EPI == 0) {
                    const int seg = col >> 10;
                    const int c = col & 1023;
                    if (seg == 0) out0[(size_t)row * 1024 + c] = v;
                    else {
                        const int b = row >> 10, s = row & 1023;
                        const int h = c >> 6, d = c & 63;
                        const size_t idx = ((size_t)((b * 16 + h) * 1024 + s)) * 64 + d;
                        if (seg == 1) present[idx] = v;
                        else          present[HEAD_ELEMS + idx] = v;
                    }
                } else out0[(size_t)row * N + col] = v;
            }
        }
}

__global__ __launch_bounds__(256) void attn64(
    const float* __restrict__ qbuf, const float* __restrict__ present,
    __hip_bfloat16* __restrict__ a_ws)
{
    const int qt = blockIdx.x, h = blockIdx.y, b = blockIdx.z;
    const int tid = threadIdx.x;
    const int wave = tid >> 6, lane = tid & 63;
    const int quad = lane >> 4, l16 = lane & 15;
    const int mb = (wave >> 1) * 32, nb = (wave & 1) * 32;
    const size_t headoff = ((size_t)(b * 16 + h)) * Ssz * HDc;
    const float* Qb = qbuf + ((size_t)(b * Ssz + qt * 64)) * NXc + h * 64;
    const float* Kp = present + headoff;
    const float* Vp = present + HEAD_ELEMS + headoff;
    __shared__ __align__(16) __hip_bfloat16 Qs[64][72];
    __shared__ __align__(16) __hip_bfloat16 Ks[64][72];
    __shared__ __align__(16) __hip_bfloat16 Vts[64][72];
    __shared__ __align__(16) __hip_bfloat16 Ps[64][72];
    __shared__ float Sc[64][65];
    __shared__ float mrow[64], lrow[64], arw[64];
#pragma unroll
    for (int it = 0; it < 2; ++it) {
        const int c = tid + it * 256;
        const int row = c >> 3, seg = c & 7;
        *reinterpret_cast<uint4*>(&Qs[row][seg * 8]) =
            cvt8(Qb + (size_t)row * NXc + seg * 8);
    }
    if (tid < 64) { mrow[tid] = -1e9f; lrow[tid] = 0.f; }
    floatx4 oacc[2][2];
#pragma unroll
    for (int i = 0; i < 2; ++i)
#pragma unroll
        for (int j = 0; j < 2; ++j)
#pragma unroll
            for (int r = 0; r < 4; ++r) oacc[i][j][r] = 0.f;
    __syncthreads();
    for (int kt = 0; kt <= qt; ++kt) {
#pragma unroll
        for (int it = 0; it < 2; ++it) {
            const int c = tid + it * 256;
            const int row = c >> 3, seg = c & 7;
            *reinterpret_cast<uint4*>(&Ks[row][seg * 8]) =
                cvt8(Kp + (size_t)(kt * 64 + row) * 64 + seg * 8);
            const float* vp = Vp + (size_t)(kt * 64 + row) * 64 + seg * 8;
            float4 v0 = *reinterpret_cast<const float4*>(vp);
            float4 v1 = *reinterpret_cast<const float4*>(vp + 4);
            Vts[seg * 8 + 0][row] = __float2bfloat16(v0.x);
            Vts[seg * 8 + 1][row] = __float2bfloat16(v0.y);
            Vts[seg * 8 + 2][row] = __float2bfloat16(v0.z);
            Vts[seg * 8 + 3][row] = __float2bfloat16(v0.w);
            Vts[seg * 8 + 4][row] = __float2bfloat16(v1.x);
            Vts[seg * 8 + 5][row] = __float2bfloat16(v1.y);
            Vts[seg * 8 + 6][row] = __float2bfloat16(v1.z);
            Vts[seg * 8 + 7][row] = __float2bfloat16(v1.w);
        }
        __syncthreads();
        floatx4 sacc[2][2];
#pragma unroll
        for (int i = 0; i < 2; ++i)
#pragma unroll
            for (int j = 0; j < 2; ++j)
#pragma unroll
                for (int r = 0; r < 4; ++r) sacc[i][j][r] = 0.f;
#pragma unroll
        for (int kd = 0; kd < 64; kd += 32) {
            short8 af[2], bf[2];
#pragma unroll
            for (int mm = 0; mm < 2; ++mm)
                af[mm] = *reinterpret_cast<const short8*>(&Qs[mb + mm * 16 + l16][kd + quad * 8]);
#pragma unroll
            for (int nn = 0; nn < 2; ++nn)
                bf[nn] = *reinterpret_cast<const short8*>(&Ks[nb + nn * 16 + l16][kd + quad * 8]);
#pragma unroll
            for (int mm = 0; mm < 2; ++mm)
#pragma unroll
                for (int nn = 0; nn < 2; ++nn)
                    sacc[mm][nn] = __builtin_amdgcn_mfma_f32_16x16x32_bf16(
                        af[mm], bf[nn], sacc[mm][nn], 0, 0, 0);
        }
        const bool diag = (kt == qt);
#pragma unroll
        for (int mm = 0; mm < 2; ++mm)
#pragma unroll
            for (int nn = 0; nn < 2; ++nn)
#pragma unroll
                for (int r = 0; r < 4; ++r) {
                    const int row = mb + mm * 16 + quad * 4 + r;
                    const int col = nb + nn * 16 + l16;
                    float v = fminf(fmaxf(sacc[mm][nn][r] * 0.125f, -1e8f), 1e8f);
                    if (diag && col > row) v = -1e9f;
                    Sc[row][col] = v;
                }
        __syncthreads();
        if (tid < 64) {
            const int r = tid;
            const float mo = mrow[r];
            float mx = mo;
            for (int c = 0; c < 64; ++c) mx = fmaxf(mx, Sc[r][c]);
            const float al = (mo <= -5e8f) ? 0.f : __expf(mo - mx);
            float sum = 0.f;
            for (int c = 0; c < 64; ++c) {
                const float sv = Sc[r][c];
                const float p = (sv <= -5e8f) ? 0.f : __expf(sv - mx);
                sum += p;
                Ps[r][c] = __float2bfloat16(p);
            }
            mrow[r] = mx;
            lrow[r] = lrow[r] * al + sum;
            arw[r]  = al;
        }
        __syncthreads();
#pragma unroll
        for (int mm = 0; mm < 2; ++mm) {
            const int rbase = mb + mm * 16 + quad * 4;
#pragma unroll
            for (int r = 0; r < 4; ++r) {
                const float al = arw[rbase + r];
                oacc[mm][0][r] *= al;
                oacc[mm][1][r] *= al;
            }
        }
#pragma unroll
        for (int kk = 0; kk < 64; kk += 32) {
            short8 pf[2], vf[2];
#pragma unroll
            for (int mm = 0; mm < 2; ++mm)
                pf[mm] = *reinterpret_cast<const short8*>(&Ps[mb + mm * 16 + l16][kk + quad * 8]);
#pragma unroll
            for (int nn = 0; nn < 2; ++nn)
                vf[nn] = *reinterpret_cast<const short8*>(&Vts[nb + nn * 16 + l16][kk + quad * 8]);
#pragma unroll
            for (int mm = 0; mm < 2; ++mm)
#pragma unroll
                for (int nn = 0; nn < 2; ++nn)
                    oacc[mm][nn] = __builtin_amdgcn_mfma_f32_16x16x32_bf16(
                        pf[mm], vf[nn], oacc[mm][nn], 0, 0, 0);
        }
        __syncthreads();
    }
#pragma unroll
    for (int mm = 0; mm < 2; ++mm)
#pragma unroll
        for (int nn = 0; nn < 2; ++nn)
#pragma unroll
            for (int r = 0; r < 4; ++r) {
                const int row = mb + mm * 16 + quad * 4 + r;
                const int col = nb + nn * 16 + l16;
                const float inv = 1.0f / fmaxf(lrow[row], 1e-20f);
                a_ws[((size_t)(b * Ssz + qt * 64 + row)) * NXc + h * 64 + col] =
                    __float2bfloat16(oacc[mm][nn][r] * inv);
            }
}

// ===========================================================================
extern "C" void kernel_launch(void* const* d_in, const int* in_sizes, int n_in,
                              void* d_out, int out_size, void* d_ws, size_t ws_size,
                              hipStream_t stream) {
    const float* x      = (const float*)d_in[0];
    const float* w_attn = (const float*)d_in[1];
    const float* b_attn = (const float*)d_in[2];
    const float* w_proj = (const float*)d_in[3];
    const float* b_proj = (const float*)d_in[4];

    float* out     = (float*)d_out;
    float* present = out + OUT_ELEMS;

    const size_t NEED = 32u * 1024u * 1024u;
    if (ws_size >= NEED) {
        // ws layout (bf16 elems):
        //   reg1 [0,4M)   : x_bf (dead after gemm128p<0>)
        //   reg2 [4M,8M)  : q_ws, then a_ws in-place (attn writes over q)
        //   reg3 [8M,12M) : unused
        //   wTa  [12M,15M): transposed w_attn
        //   wTp  [15M,16M): transposed w_proj
        // k_ws/vt_ws (8 MB each, bf16) live in the `out` region of d_out:
        // written by gemm128p<0>'s epilogue, read by attn_v4, dead before
        // gemm128p<1> overwrites out at the end. Exactly fills 16 MB.
        __hip_bfloat16* reg1 = (__hip_bfloat16*)d_ws;
        __hip_bfloat16* reg2 = reg1 + 4194304;
        __hip_bfloat16* reg3 = reg2 + 4194304;
        __hip_bfloat16* wTa  = reg3 + 4194304;
        __hip_bfloat16* wTp  = wTa + 3145728;
        __hip_bfloat16* kws  = (__hip_bfloat16*)out;
        __hip_bfloat16* vtws = kws + 4194304;

        prep_kernel<<<3072, 256, 0, stream>>>(x, reg1, w_attn, wTa, w_proj, wTp);

        gemm128p<0><<<dim3(24, 32), 256, 0, stream>>>(
            reg1, wTa, b_attn, nullptr, reg2, present, kws, vtws,
            4096, 3072, 1024);

        attn_v4<<<dim3(8, 16, 4), 256, 0, stream>>>(reg2, kws, vtws, reg2);

        gemm128p<1><<<dim3(8, 32), 256, 0, stream>>>(
            reg2, wTp, b_proj, out, nullptr, nullptr, nullptr, nullptr,
            4096, 1024, 1024);
    } else {
        // round-3 fallback (needs 8 MB ws)
        __hip_bfloat16* a_ws = (__hip_bfloat16*)d_ws;
        hipMemsetAsync(d_ws, 0, (size_t)OUT_ELEMS * sizeof(__hip_bfloat16), stream);
        gemm64<0><<<dim3(48, 64), 256, 0, stream>>>(x, w_attn, b_attn, out, present,
                                                    4096, 3072, 1024);
        attn64<<<dim3(16, 16, 4), 256, 0, stream>>>(out, present, a_ws);
        gemm64<1><<<dim3(16, 64), 256, 0, stream>>>(a_ws, w_proj, b_proj, out, nullptr,
                                                    4096, 1024, 1024);
    }
}